// Round 1
// baseline (2002.464 us; speedup 1.0000x reference)
//
#include <hip/hip_runtime.h>
#include <hip/hip_bf16.h>
#include <math.h>

// Problem dims
#define TZc 512
#define TUc 512
#define Bc  64
#define Hc  512
#define Ec  256
#define Vc  3000
#define Dc  5
#define KVc (Vc + TZc)   // 3512

// ---------------------------------------------------------------------------
// small helpers
// ---------------------------------------------------------------------------
__global__ void fill_gru_in(const int* __restrict__ mt,
                            const float* __restrict__ embW,
                            const float* __restrict__ degree,
                            float* __restrict__ gru_in) {
    int b = blockIdx.x;
    int t = threadIdx.x;                  // 256 threads == Ec
    int idx = mt[b];
    gru_in[b * 1285 + t] = embW[idx * Ec + t];
    if (t < Dc) gru_in[b * 1285 + 1280 + t] = degree[b * Dc + t];
}

// ---------------------------------------------------------------------------
// gemm64_n : C[64 x N] = A[64 x K] @ B[K x N] + bias   (B row-major K x N)
// ---------------------------------------------------------------------------
__global__ __launch_bounds__(256) void gemm64_n(
    const float* __restrict__ A, int lda,
    const float* __restrict__ Bm, int ldb,
    const float* __restrict__ bias,
    float* __restrict__ C, int ldc,
    int N, int K) {
    __shared__ float As[16][68];
    __shared__ float Bs[16][68];
    int tid = threadIdx.x;
    int tx = tid & 15, ty = tid >> 4;
    int jbase = blockIdx.x * 64;
    float acc[4][4] = {};
    for (int k0 = 0; k0 < K; k0 += 16) {
        {   // A tile 64 x 16
            int r = tid >> 2, kk0 = (tid & 3) * 4;
#pragma unroll
            for (int i = 0; i < 4; i++) {
                int k = k0 + kk0 + i;
                As[kk0 + i][r] = (k < K) ? A[r * lda + k] : 0.f;
            }
        }
        {   // B tile 16 x 64
            int kk = tid >> 4, j0 = (tid & 15) * 4;
#pragma unroll
            for (int i = 0; i < 4; i++) {
                int j = jbase + j0 + i;
                Bs[kk][j0 + i] = ((k0 + kk) < K && j < N) ? Bm[(size_t)(k0 + kk) * ldb + j] : 0.f;
            }
        }
        __syncthreads();
#pragma unroll
        for (int kk = 0; kk < 16; kk++) {
            float a[4], bv[4];
#pragma unroll
            for (int i = 0; i < 4; i++) a[i] = As[kk][ty * 4 + i];
#pragma unroll
            for (int i = 0; i < 4; i++) bv[i] = Bs[kk][tx * 4 + i];
#pragma unroll
            for (int mi = 0; mi < 4; mi++)
#pragma unroll
                for (int ni = 0; ni < 4; ni++)
                    acc[mi][ni] = fmaf(a[mi], bv[ni], acc[mi][ni]);
        }
        __syncthreads();
    }
#pragma unroll
    for (int mi = 0; mi < 4; mi++) {
        int m = ty * 4 + mi;
#pragma unroll
        for (int ni = 0; ni < 4; ni++) {
            int j = jbase + tx * 4 + ni;
            if (j < N) C[(size_t)m * ldc + j] = acc[mi][ni] + (bias ? bias[j] : 0.f);
        }
    }
}

// ---------------------------------------------------------------------------
// gemm64_t : C[64 x N] = A[64 x K] @ Bt^T + bias   (Bt row-major N x K)
// ---------------------------------------------------------------------------
__global__ __launch_bounds__(256) void gemm64_t(
    const float* __restrict__ A, int lda,
    const float* __restrict__ Bt, int ldk,
    const float* __restrict__ bias,
    float* __restrict__ C, int ldc,
    int N, int K) {
    __shared__ float As[16][68];
    __shared__ float Bs[16][68];
    int tid = threadIdx.x;
    int tx = tid & 15, ty = tid >> 4;
    int jbase = blockIdx.x * 64;
    float acc[4][4] = {};
    for (int k0 = 0; k0 < K; k0 += 16) {
        {
            int r = tid >> 2, kk0 = (tid & 3) * 4;
#pragma unroll
            for (int i = 0; i < 4; i++) {
                int k = k0 + kk0 + i;
                As[kk0 + i][r] = (k < K) ? A[r * lda + k] : 0.f;
            }
        }
        {
            int j = tid >> 2, kk0 = (tid & 3) * 4;
#pragma unroll
            for (int i = 0; i < 4; i++) {
                int k = k0 + kk0 + i;
                Bs[kk0 + i][j] = (k < K) ? Bt[(size_t)(jbase + j) * ldk + k] : 0.f;
            }
        }
        __syncthreads();
#pragma unroll
        for (int kk = 0; kk < 16; kk++) {
            float a[4], bv[4];
#pragma unroll
            for (int i = 0; i < 4; i++) a[i] = As[kk][ty * 4 + i];
#pragma unroll
            for (int i = 0; i < 4; i++) bv[i] = Bs[kk][tx * 4 + i];
#pragma unroll
            for (int mi = 0; mi < 4; mi++)
#pragma unroll
                for (int ni = 0; ni < 4; ni++)
                    acc[mi][ni] = fmaf(a[mi], bv[ni], acc[mi][ni]);
        }
        __syncthreads();
    }
#pragma unroll
    for (int mi = 0; mi < 4; mi++) {
        int m = ty * 4 + mi;
#pragma unroll
        for (int ni = 0; ni < 4; ni++) {
            int j = jbase + tx * 4 + ni;
            if (j < N) C[(size_t)m * ldc + j] = acc[mi][ni] + (bias ? bias[j] : 0.f);
        }
    }
}

// ---------------------------------------------------------------------------
// big_gemm : A (32768 x 512) @ B (512 x 512), 128x128 tile, 8x8/thread
// EPI==0 : e[b,t] += sum_h tanh(acc + hW[b,h]) * v[h]   (atomic partial)
// EPI==1 : out[row,h] = tanh(acc + bias[h])             (zc store)
// ---------------------------------------------------------------------------
template <int EPI>
__global__ __launch_bounds__(256) void big_gemm(
    const float* __restrict__ A,
    const float* __restrict__ Bm,
    const float* __restrict__ p1,   // EPI0: hW (64x512)  EPI1: bias (512)
    const float* __restrict__ p2,   // EPI0: v  (512)     EPI1: unused
    float* __restrict__ out)        // EPI0: e (64 x 512) EPI1: zc (M x 512)
{
    __shared__ float As[16][132];
    __shared__ float Bs[16][132];
    int tid = threadIdx.x;
    int tx = tid & 15, ty = tid >> 4;
    int rowbase = blockIdx.y * 128;
    int colbase = blockIdx.x * 128;
    float acc[8][8] = {};
    for (int k0 = 0; k0 < 512; k0 += 16) {
        {   // A tile: 128 rows x 16 k  (transposed into LDS)
            int r = tid >> 1, kk0 = (tid & 1) * 8;
            const float* Ap = A + (size_t)(rowbase + r) * 512 + k0 + kk0;
            float4 a0 = *(const float4*)Ap;
            float4 a1 = *(const float4*)(Ap + 4);
            As[kk0 + 0][r] = a0.x; As[kk0 + 1][r] = a0.y;
            As[kk0 + 2][r] = a0.z; As[kk0 + 3][r] = a0.w;
            As[kk0 + 4][r] = a1.x; As[kk0 + 5][r] = a1.y;
            As[kk0 + 6][r] = a1.z; As[kk0 + 7][r] = a1.w;
        }
        {   // B tile: 16 k x 128 cols
            int kk = tid >> 4, j0 = (tid & 15) * 8;
            const float* Bp = Bm + (size_t)(k0 + kk) * 512 + colbase + j0;
            *(float4*)&Bs[kk][j0]     = *(const float4*)Bp;
            *(float4*)&Bs[kk][j0 + 4] = *(const float4*)(Bp + 4);
        }
        __syncthreads();
#pragma unroll
        for (int kk = 0; kk < 16; kk++) {
            float av[8], bv[8];
#pragma unroll
            for (int i = 0; i < 8; i++) av[i] = As[kk][ty * 8 + i];
#pragma unroll
            for (int i = 0; i < 8; i++) bv[i] = Bs[kk][tx * 8 + i];
#pragma unroll
            for (int mi = 0; mi < 8; mi++)
#pragma unroll
                for (int ni = 0; ni < 8; ni++)
                    acc[mi][ni] = fmaf(av[mi], bv[ni], acc[mi][ni]);
        }
        __syncthreads();
    }

    if constexpr (EPI == 0) {
        __shared__ float red[128][17];
#pragma unroll
        for (int mi = 0; mi < 8; mi++) {
            int row = rowbase + ty * 8 + mi;
            int b = row & 63;
            float rs = 0.f;
#pragma unroll
            for (int ni = 0; ni < 8; ni++) {
                int h = colbase + tx * 8 + ni;
                rs += tanhf(acc[mi][ni] + p1[b * Hc + h]) * p2[h];
            }
            red[ty * 8 + mi][tx] = rs;
        }
        __syncthreads();
        if (tid < 128) {
            float s = 0.f;
#pragma unroll
            for (int x = 0; x < 16; x++) s += red[tid][x];
            int row = rowbase + tid;
            int t = row >> 6, b = row & 63;
            atomicAdd(&out[b * TZc + t], s);
        }
    } else {
#pragma unroll
        for (int mi = 0; mi < 8; mi++) {
            int row = rowbase + ty * 8 + mi;
            float4 o0, o1;
            int h0c = colbase + tx * 8;
            o0.x = tanhf(acc[mi][0] + p1[h0c + 0]);
            o0.y = tanhf(acc[mi][1] + p1[h0c + 1]);
            o0.z = tanhf(acc[mi][2] + p1[h0c + 2]);
            o0.w = tanhf(acc[mi][3] + p1[h0c + 3]);
            o1.x = tanhf(acc[mi][4] + p1[h0c + 4]);
            o1.y = tanhf(acc[mi][5] + p1[h0c + 5]);
            o1.z = tanhf(acc[mi][6] + p1[h0c + 6]);
            o1.w = tanhf(acc[mi][7] + p1[h0c + 7]);
            float* op = out + (size_t)row * 512 + h0c;
            *(float4*)op = o0;
            *(float4*)(op + 4) = o1;
        }
    }
}

// ---------------------------------------------------------------------------
// softmax over t (length 512) + ctx[b,h] = sum_t a[t] * enc[t,b,h]
// writes ctx into two destinations (gru_in slot and cat2 slot)
// ---------------------------------------------------------------------------
__global__ __launch_bounds__(256) void softmax_ctx(
    const float* __restrict__ e, const float* __restrict__ enc,
    float* __restrict__ dst1, int ld1, int off1,
    float* __restrict__ dst2, int ld2, int off2) {
    int b = blockIdx.x, tid = threadIdx.x;
    __shared__ float a[512];
    __shared__ float red[256];
    float v1 = e[b * 512 + tid], v2 = e[b * 512 + 256 + tid];
    float mx = fmaxf(v1, v2);
    red[tid] = mx; __syncthreads();
    for (int s = 128; s; s >>= 1) { if (tid < s) red[tid] = fmaxf(red[tid], red[tid + s]); __syncthreads(); }
    float M = red[0]; __syncthreads();
    float e1 = expf(v1 - M), e2 = expf(v2 - M);
    red[tid] = e1 + e2; __syncthreads();
    for (int s = 128; s; s >>= 1) { if (tid < s) red[tid] += red[tid + s]; __syncthreads(); }
    float inv = 1.f / red[0];
    a[tid] = e1 * inv; a[256 + tid] = e2 * inv;
    __syncthreads();
    float c1 = 0.f, c2 = 0.f;
    int h1i = tid, h2i = tid + 256;
    for (int t = 0; t < 512; t++) {
        float av = a[t];
        const float* ep = enc + ((size_t)t * 64 + b) * 512;
        c1 = fmaf(av, ep[h1i], c1);
        c2 = fmaf(av, ep[h2i], c2);
    }
    dst1[(size_t)b * ld1 + off1 + h1i] = c1;
    dst1[(size_t)b * ld1 + off1 + h2i] = c2;
    dst2[(size_t)b * ld2 + off2 + h1i] = c1;
    dst2[(size_t)b * ld2 + off2 + h2i] = c2;
}

// ---------------------------------------------------------------------------
// GRU combine
// ---------------------------------------------------------------------------
__global__ void gru_combine(const float* __restrict__ gi, const float* __restrict__ gh,
                            const float* __restrict__ h0,
                            float* __restrict__ out1, float* __restrict__ out2,
                            float* __restrict__ cat2, float* __restrict__ h1ws) {
    int i = blockIdx.x * 256 + threadIdx.x;     // < 64*512
    int b = i >> 9, h = i & 511;
    float ir = gi[(size_t)b * 1536 + h], iz = gi[(size_t)b * 1536 + 512 + h], in_ = gi[(size_t)b * 1536 + 1024 + h];
    float hr = gh[(size_t)b * 1536 + h], hz = gh[(size_t)b * 1536 + 512 + h], hn = gh[(size_t)b * 1536 + 1024 + h];
    float r = 1.f / (1.f + expf(-(ir + hr)));
    float z = 1.f / (1.f + expf(-(iz + hz)));
    float n = tanhf(in_ + r * hn);
    float hv = (1.f - z) * n + z * h0[i];
    out1[i] = hv; out2[i] = hv;
    cat2[(size_t)b * 1536 + 1024 + h] = hv;
    h1ws[i] = hv;
}

// ---------------------------------------------------------------------------
// cs[b,t] = sum_h zc[t,b,h] * h1[b,h]   (one wave per (b,t))
// ---------------------------------------------------------------------------
__global__ void cs_kernel(const float* __restrict__ zc, const float* __restrict__ h1,
                          float* __restrict__ cs) {
    int gid = blockIdx.x * blockDim.x + threadIdx.x;
    int wid = gid >> 6;
    int lane = threadIdx.x & 63;
    int b = wid & 63, t = wid >> 6;
    const float* zp = zc + ((size_t)t * 64 + b) * 512;
    const float* hp = h1 + (size_t)b * 512;
    float acc = 0.f;
#pragma unroll
    for (int k = 0; k < 512; k += 64) acc = fmaf(zp[k + lane], hp[k + lane], acc);
    for (int off = 32; off; off >>= 1) acc += __shfl_down(acc, off);
    if (lane == 0) cs[b * TZc + t] = acc;
}

__global__ void row_max_ecs(const float* __restrict__ cs, float* __restrict__ ecs,
                            float* __restrict__ mrow) {
    int b = blockIdx.x, tid = threadIdx.x;
    __shared__ float red[256];
    float v1 = cs[b * 512 + tid], v2 = cs[b * 512 + 256 + tid];
    red[tid] = fmaxf(v1, v2); __syncthreads();
    for (int s = 128; s; s >>= 1) { if (tid < s) red[tid] = fmaxf(red[tid], red[tid + s]); __syncthreads(); }
    float M = red[0];
    ecs[b * 512 + tid] = expf(v1 - M);
    ecs[b * 512 + 256 + tid] = expf(v2 - M);
    if (tid == 0) mrow[b] = M;
}

// ---------------------------------------------------------------------------
// zpart[tc][b][v] = sum_{t in chunk tc} ecs[b,t]*sparse[b,t,v]  (float4 over v)
// ---------------------------------------------------------------------------
__global__ __launch_bounds__(256) void zpart_kernel(
    const float* __restrict__ ecs, const float* __restrict__ sparse,
    float* __restrict__ zpart) {
    int b = blockIdx.y;
    int tc = blockIdx.z;
    __shared__ float se[128];
    if (threadIdx.x < 128) se[threadIdx.x] = ecs[b * 512 + tc * 128 + threadIdx.x];
    __syncthreads();
    int v4 = blockIdx.x * 256 + threadIdx.x;    // float4 index, 878 total
    if (v4 >= 878) return;
    const float4* sp = (const float4*)sparse + ((size_t)b * 512 + tc * 128) * 878 + v4;
    float4 acc = {0.f, 0.f, 0.f, 0.f};
    for (int t = 0; t < 128; t++) {
        float s = se[t];
        float4 x = sp[(size_t)t * 878];
        acc.x = fmaf(s, x.x, acc.x); acc.y = fmaf(s, x.y, acc.y);
        acc.z = fmaf(s, x.z, acc.z); acc.w = fmaf(s, x.w, acc.w);
    }
    ((float4*)zpart)[((size_t)tc * 64 + b) * 878 + v4] = acc;
}

// ---------------------------------------------------------------------------
// final: z_copy = log(sum zpart)+m ; softmax over [gen(3000) | z_copy(3512)]
// proba[j<3000] = gen_sc + cpy_sc ; proba[3000+i] = cpy_sc
// ---------------------------------------------------------------------------
__global__ __launch_bounds__(256) void final_softmax(
    const float* __restrict__ gen, const float* __restrict__ zpart,
    const float* __restrict__ mrow, float* __restrict__ proba) {
    int b = blockIdx.x, tid = threadIdx.x;
    __shared__ float sc[6512];
    __shared__ float red[256];
    for (int j = tid; j < 3000; j += 256) sc[j] = gen[(size_t)b * 3000 + j];
    float mb = mrow[b];
    for (int v = tid; v < 3512; v += 256) {
        float s = zpart[((size_t)0 * 64 + b) * 3512 + v] + zpart[((size_t)1 * 64 + b) * 3512 + v]
                + zpart[((size_t)2 * 64 + b) * 3512 + v] + zpart[((size_t)3 * 64 + b) * 3512 + v];
        sc[3000 + v] = logf(s) + mb;
    }
    __syncthreads();
    float mx = -INFINITY;
    for (int i = tid; i < 6512; i += 256) mx = fmaxf(mx, sc[i]);
    red[tid] = mx; __syncthreads();
    for (int s = 128; s; s >>= 1) { if (tid < s) red[tid] = fmaxf(red[tid], red[tid + s]); __syncthreads(); }
    float M = red[0]; __syncthreads();
    float sum = 0.f;
    for (int i = tid; i < 6512; i += 256) sum += expf(sc[i] - M);
    red[tid] = sum; __syncthreads();
    for (int s = 128; s; s >>= 1) { if (tid < s) red[tid] += red[tid + s]; __syncthreads(); }
    float inv = 1.f / red[0];
    for (int j = tid; j < 3000; j += 256)
        proba[(size_t)b * KVc + j] = (expf(sc[j] - M) + expf(sc[3000 + j] - M)) * inv;
    for (int i = tid; i < 512; i += 256)
        proba[(size_t)b * KVc + 3000 + i] = expf(sc[6000 + i] - M) * inv;
}

// ---------------------------------------------------------------------------
extern "C" void kernel_launch(void* const* d_in, const int* in_sizes, int n_in,
                              void* d_out, int out_size, void* d_ws, size_t ws_size,
                              hipStream_t stream) {
    const float* z_enc   = (const float*)d_in[0];
    const float* u_enc   = (const float*)d_in[1];
    const int*   m_t     = (const int*)  d_in[2];
    const float* degree  = (const float*)d_in[3];
    const float* h0      = (const float*)d_in[4];   // last_hidden (1,B,H)
    const float* sparse  = (const float*)d_in[5];
    const float* emb_W   = (const float*)d_in[6];
    const float* Wz      = (const float*)d_in[7];
    const float* bz      = (const float*)d_in[8];
    const float* vz      = (const float*)d_in[9];
    const float* Wu      = (const float*)d_in[10];
    const float* bu      = (const float*)d_in[11];
    const float* vu      = (const float*)d_in[12];
    const float* W_ih    = (const float*)d_in[13];
    const float* W_hh    = (const float*)d_in[14];
    const float* b_ih    = (const float*)d_in[15];
    const float* b_hh    = (const float*)d_in[16];
    const float* W_proj  = (const float*)d_in[17];
    const float* b_proj  = (const float*)d_in[18];
    const float* Wc2     = (const float*)d_in[19];
    const float* bc2     = (const float*)d_in[20];

    float* dout = (float*)d_out;    // proba (64x3512) | h1 (64x512) | h1 (64x512)

    // workspace layout (floats)
    float* w = (float*)d_ws;
    float* zc     = w;                w += (size_t)TZc * Bc * Hc;   // 16777216
    float* e_z    = w;                w += Bc * TZc;                // 32768
    float* e_u    = w;                w += Bc * TUc;                // 32768
    float* hWz    = w;                w += Bc * Hc;
    float* hWu    = w;                w += Bc * Hc;
    float* gru_in = w;                w += Bc * 1285;
    float* cat2   = w;                w += Bc * 1536;
    float* gi     = w;                w += Bc * 1536;
    float* gh     = w;                w += Bc * 1536;
    float* h1ws   = w;                w += Bc * Hc;
    float* gen    = w;                w += Bc * Vc;
    float* cs     = w;                w += Bc * TZc;
    float* ecs    = w;                w += Bc * TZc;
    float* mrow   = w;                w += 64;
    float* zpart  = w;                w += 4 * (size_t)Bc * KVc;

    // 1. zero the atomic e buffers
    hipMemsetAsync(e_z, 0, (size_t)2 * Bc * TZc * sizeof(float), stream);

    // 2. embedding gather + degree into gru_in
    fill_gru_in<<<Bc, 256, 0, stream>>>(m_t, emb_W, degree, gru_in);

    // 3. hWz = h0 @ Wz[:H] + bz ; hWu = h0 @ Wu[:H] + bu
    gemm64_n<<<8, 256, 0, stream>>>(h0, Hc, Wz, Hc, bz, hWz, Hc, Hc, Hc);
    gemm64_n<<<8, 256, 0, stream>>>(h0, Hc, Wu, Hc, bu, hWu, Hc, Hc, Hc);

    // 4. the three big GEMMs
    dim3 bgrid(4, 256);
    big_gemm<0><<<bgrid, 256, 0, stream>>>(z_enc, Wz + (size_t)Hc * Hc, hWz, vz, e_z);
    big_gemm<1><<<bgrid, 256, 0, stream>>>(z_enc, Wc2, bc2, nullptr, zc);
    big_gemm<0><<<bgrid, 256, 0, stream>>>(u_enc, Wu + (size_t)Hc * Hc, hWu, vu, e_u);

    // 5. attention softmax + context (writes gru_in slot and cat2 slot)
    softmax_ctx<<<Bc, 256, 0, stream>>>(e_z, z_enc, gru_in, 1285, 768, cat2, 1536, 0);
    softmax_ctx<<<Bc, 256, 0, stream>>>(e_u, u_enc, gru_in, 1285, 256, cat2, 1536, 512);

    // 6. GRU gate matmuls (B transposed) + combine
    gemm64_t<<<24, 256, 0, stream>>>(gru_in, 1285, W_ih, 1285, b_ih, gi, 1536, 1536, 1285);
    gemm64_t<<<24, 256, 0, stream>>>(h0, Hc, W_hh, Hc, b_hh, gh, 1536, 1536, Hc);
    gru_combine<<<128, 256, 0, stream>>>(gi, gh, h0,
                                         dout + (size_t)Bc * KVc,
                                         dout + (size_t)Bc * KVc + Bc * Hc,
                                         cat2, h1ws);

    // 7. gen_score = [z_ctx|u_ctx|h1] @ W_proj + b_proj
    gemm64_n<<<47, 256, 0, stream>>>(cat2, 1536, W_proj, Vc, b_proj, gen, Vc, Vc, 1536);

    // 8. cs, ecs, copy scores
    cs_kernel<<<8192, 256, 0, stream>>>(zc, h1ws, cs);
    row_max_ecs<<<Bc, 256, 0, stream>>>(cs, ecs, mrow);
    zpart_kernel<<<dim3(4, Bc, 4), 256, 0, stream>>>(ecs, sparse, zpart);

    // 9. final fused softmax + merge
    final_softmax<<<Bc, 256, 0, stream>>>(gen, zpart, mrow, dout);
}